// Round 17
// baseline (126.614 us; speedup 1.0000x reference)
//
#include <hip/hip_runtime.h>

#define B_ 256
#define K_ 10
#define I_ 1152
#define O_ 16
#define C_ 8
#define BKO (B_*K_*O_)   // 40960
#define NX 72            // i0 blocks (uhat grid.x)

static __device__ __forceinline__ unsigned short f32_bf16(float f) {
    unsigned int u = __float_as_uint(f);
    u += 0x7FFFu + ((u >> 16) & 1u);           // round-to-nearest-even
    return (unsigned short)(u >> 16);
}

// DPP butterfly add step (full-rate VALU; ctrl is a compile-time const)
template <int CTRL>
static __device__ __forceinline__ float dpp_add(float v) {
    int x = __builtin_amdgcn_update_dpp(0, __float_as_int(v), CTRL, 0xF, 0xF, true);
    return v + __int_as_float(x);
}
// sum over each 16-lane DPP row: xor1, xor2, half-mirror, mirror
static __device__ __forceinline__ float row16_sum(float v) {
    v = dpp_add<0xB1>(v);     // quad_perm(1,0,3,2)  : + lane^1
    v = dpp_add<0x4E>(v);     // quad_perm(2,3,0,1)  : + lane^2
    v = dpp_add<0x141>(v);    // row_half_mirror     : + other quad
    v = dpp_add<0x140>(v);    // row_mirror          : + other half-row
    return v;
}
// sum over the 4 lanes of each quad (the og group) — VALU-rate, no LDS pipe
static __device__ __forceinline__ float quad4_sum(float v) {
    v = dpp_add<0xB1>(v);     // + lane^1
    v = dpp_add<0x4E>(v);     // + lane^2
    return v;
}

// ---------------------------------------------------------------------------
// uhat_kernel v7 (FROZEN from round 15): u[b][k][i][o] = bf16(w·x) + pass-1
// partials part[x][k][b][o].  grid (72, 4, 10); 256 thr; 4 b per thread.
// ---------------------------------------------------------------------------
__global__ __launch_bounds__(256) void uhat_kernel(
    const float* __restrict__ x, const float* __restrict__ w,
    unsigned short* __restrict__ u, float* __restrict__ part)
{
    __shared__ float w_lds[16 * 132];   // [ii][o*8+c], stride 132: 2-way max
    __shared__ float p_lds[64 * 17];    // [b_local*17 + o], padded rows
    const int t   = threadIdx.x;
    const int i_l = t & 15, tg = t >> 4;
    const int i0  = blockIdx.x * 16;
    const int b0  = blockIdx.y * 64 + tg * 4;
    const int k   = blockIdx.z;
    const int i   = i0 + i_l;
    const bool row_leader = (i_l == 0);

    float4 xr[4][2];
#pragma unroll
    for (int bb = 0; bb < 4; bb++) {
        const float4* xp = (const float4*)(x + ((size_t)(b0 + bb) * I_ + i) * C_);
        xr[bb][0] = xp[0];
        xr[bb][1] = xp[1];
    }

    {
        const float4* ws = (const float4*)(w + ((size_t)k * I_ + i0) * O_ * C_);
#pragma unroll
        for (int r = 0; r < 2; r++) {
            int idx = r * 256 + t;               // float4 index in 16x128 slab
            int ii = idx >> 5, rem = idx & 31;
            *(float4*)&w_lds[ii * 132 + rem * 4] = ws[idx];
        }
    }
    __syncthreads();

    unsigned int pk[4][8];
#pragma unroll
    for (int oo = 0; oo < 8; oo++) {             // o-pair index
        float d[4][2];
#pragma unroll
        for (int h = 0; h < 2; h++) {
            const int o = oo * 2 + h;
            const float4 w0 = *(const float4*)&w_lds[i_l * 132 + o * 8];
            const float4 w1 = *(const float4*)&w_lds[i_l * 132 + o * 8 + 4];
#pragma unroll
            for (int bb = 0; bb < 4; bb++) {
                d[bb][h] = w0.x*xr[bb][0].x + w0.y*xr[bb][0].y
                         + w0.z*xr[bb][0].z + w0.w*xr[bb][0].w
                         + w1.x*xr[bb][1].x + w1.y*xr[bb][1].y
                         + w1.z*xr[bb][1].z + w1.w*xr[bb][1].w;
            }
        }
        // pass-1 fold: i-sum via DPP rows (16 lanes = the 16 i's)
#pragma unroll
        for (int bb = 0; bb < 4; bb++) {
#pragma unroll
            for (int h = 0; h < 2; h++) {
                const float rs = row16_sum(d[bb][h]);
                if (row_leader)
                    p_lds[(tg * 4 + bb) * 17 + oo * 2 + h] = rs;
            }
        }
#pragma unroll
        for (int bb = 0; bb < 4; bb++)
            pk[bb][oo] = (unsigned int)f32_bf16(d[bb][0]) |
                         ((unsigned int)f32_bf16(d[bb][1]) << 16);
    }
    // fused 32 B u store per (b,k,i)
#pragma unroll
    for (int bb = 0; bb < 4; bb++) {
        unsigned int* dst = (unsigned int*)
            (u + (((size_t)(b0 + bb) * K_ + k) * I_ + i) * O_);
        *(uint4*)(dst)     = make_uint4(pk[bb][0], pk[bb][1], pk[bb][2], pk[bb][3]);
        *(uint4*)(dst + 4) = make_uint4(pk[bb][4], pk[bb][5], pk[bb][6], pk[bb][7]);
    }

    // dense partial store: part[x][k][b][o] — wave writes 1024 B contiguous
    __syncthreads();
    {
        const int bl = t >> 2, o4 = (t & 3) * 4;     // b_local, o-quad
        float4 v;
        v.x = p_lds[bl * 17 + o4 + 0];
        v.y = p_lds[bl * 17 + o4 + 1];
        v.z = p_lds[bl * 17 + o4 + 2];
        v.w = p_lds[bl * 17 + o4 + 3];
        *(float4*)&part[(((size_t)blockIdx.x * K_ + k) * 256
                         + blockIdx.y * 64 + bl) * O_ + o4] = v;
    }
}

// ---------------------------------------------------------------------------
// stage: async global->LDS copy of one 40 KB u-chunk (128 i x 10 k x 32 B).
// 40 rows of 1 KB; wave wv DMAs rows 5*wv .. 5*wv+4 via global_load_lds
// width=16 (lane L -> lds_base + L*16, matching gptr = row_base + L*16 B).
// ---------------------------------------------------------------------------
static __device__ __forceinline__ void stage(
    const unsigned short* __restrict__ ub0, int ic,
    unsigned short* __restrict__ buf, int wv, int lane)
{
#pragma unroll
    for (int j = 0; j < 5; j++) {
        const int r = wv * 5 + j;
        const int k = r >> 2, q = r & 3;
        const unsigned short* gp =
            ub0 + ((size_t)k * I_ + ic * 128 + q * 32) * O_ + lane * 8;
        unsigned short* lp = buf + r * 512;
        __builtin_amdgcn_global_load_lds(
            (const __attribute__((address_space(1))) void*)gp,
            (__attribute__((address_space(3))) void*)lp,
            16, 0, 0);
    }
}

// ---------------------------------------------------------------------------
// sweep v9: LDS-staged, double-buffered routing pass (m97-style pipeline).
// stage(ic+1) is in flight while chunk ic is computed from LDS; the
// end-of-chunk __syncthreads drains it (mostly hidden under ~500 cyc of
// compute).  No P/Q register buffers -> ~90 VGPR, no spill risk.
// thread: og = t&3 (o-quad), i_l = t>>2 in [0,128); LDS read per (k):
// ds_read_b64 at k*4096 + i_l*32 + og*8 bytes (quad-broadcast friendly).
// ---------------------------------------------------------------------------
static __device__ __forceinline__ void sweep(
    const unsigned short* __restrict__ ub0,
    unsigned short (*__restrict__ ubuf)[20480],
    const float* __restrict__ v_lds,
    int i_l, int og, int wv, int lane, float acc[K_][4])
{
#pragma unroll
    for (int k = 0; k < K_; k++)
#pragma unroll
        for (int j = 0; j < 4; j++) acc[k][j] = 0.f;

    stage(ub0, 0, ubuf[0], wv, lane);
    __syncthreads();

#pragma unroll 1
    for (int ic = 0; ic < 9; ic++) {
        if (ic + 1 < 9)
            stage(ub0, ic + 1, ubuf[(ic + 1) & 1], wv, lane);

        const unsigned short* bp = ubuf[ic & 1] + i_l * 16 + og * 4;
        uint2 P[K_];
#pragma unroll
        for (int k = 0; k < K_; k++)
            P[k] = *(const uint2*)(bp + k * 2048);

        float c[K_];
        float Z = 0.f;
#pragma unroll
        for (int k = 0; k < K_; k++) {
            const float f0 = __uint_as_float(P[k].x << 16);
            const float f1 = __uint_as_float(P[k].x & 0xffff0000u);
            const float f2 = __uint_as_float(P[k].y << 16);
            const float f3 = __uint_as_float(P[k].y & 0xffff0000u);
            const float* vk = &v_lds[k * 16 + og * 4];
            float lk = f0 * vk[0] + f1 * vk[1] + f2 * vk[2] + f3 * vk[3];
            lk = quad4_sum(lk);           // DPP, VALU-rate
            c[k] = __expf(lk);
            Z += c[k];
        }
        const float inv = 1.0f / Z;
#pragma unroll
        for (int k = 0; k < K_; k++) {
            const float ck = c[k] * inv;
            acc[k][0] = fmaf(ck, __uint_as_float(P[k].x << 16),         acc[k][0]);
            acc[k][1] = fmaf(ck, __uint_as_float(P[k].x & 0xffff0000u), acc[k][1]);
            acc[k][2] = fmaf(ck, __uint_as_float(P[k].y << 16),         acc[k][2]);
            acc[k][3] = fmaf(ck, __uint_as_float(P[k].y & 0xffff0000u), acc[k][3]);
        }
        __syncthreads();   // buffer-reuse guard + drains stage(ic+1)
    }
}

// reduce acc over the 16 i-positions of each wave; deposit per-wave sums.
static __device__ __forceinline__ void block_reduce(
    float acc[K_][4], float* __restrict__ red, int lane, int wv)
{
#pragma unroll
    for (int k = 0; k < K_; k++)
#pragma unroll
        for (int j = 0; j < 4; j++) {
            float a = acc[k][j];
            a += __shfl_xor(a, 4);  a += __shfl_xor(a, 8);
            a += __shfl_xor(a, 16); a += __shfl_xor(a, 32);
            acc[k][j] = a;
        }
    if (lane < 4) {
#pragma unroll
        for (int k = 0; k < K_; k++)
            *(float4*)&red[wv * 160 + k * 16 + lane * 4] =
                make_float4(acc[k][0], acc[k][1], acc[k][2], acc[k][3]);
    }
    __syncthreads();
}

// sum the 8 per-wave partials for element t (t < 160)
static __device__ __forceinline__ float sum8(const float* __restrict__ red, int t)
{
    float s = 0.f;
#pragma unroll
    for (int wgi = 0; wgi < 8; wgi++) s += red[wgi * 160 + t];
    return s;
}

// squash for element t<160: 16-lane o-group norm reduce
static __device__ __forceinline__ float squash_v(float s) {
    float n2 = s * s;
    n2 += __shfl_xor(n2, 1); n2 += __shfl_xor(n2, 2);
    n2 += __shfl_xor(n2, 4); n2 += __shfl_xor(n2, 8);
    const float norm = sqrtf(n2);
    return s * (n2 / (1.0f + n2) / (norm + 1e-9f));
}

// ---------------------------------------------------------------------------
// route_all v9: passes 2+3 with async-LDS-staged sweeps; pass 1 from part.
// grid (256), 512 thr (8 waves).  LDS: 2x40 KB u ping-pong + 6.6 KB misc.
// ---------------------------------------------------------------------------
__global__ __launch_bounds__(512) void route_all(
    const unsigned short* __restrict__ u, const float* __restrict__ part,
    float* __restrict__ out)
{
    __shared__ unsigned short ubuf[2][20480];   // 2 x 40 KB chunk buffers
    __shared__ float red[8 * 160];
    __shared__ float v_lds[160];
    __shared__ float v1_lds[160];

    const int t    = threadIdx.x;
    const int og   = t & 3, i_l = t >> 2;   // og: o-quad, i_l in 0..127
    const int b    = blockIdx.x;
    const int lane = t & 63, wv = t >> 6;

    const unsigned short* ub0 = u + (size_t)b * K_ * I_ * O_;
    float acc[K_][4];

    // ---- prologue: s1 = sum over the 72 i-blocks; v1 = squash(s1/K) ----
    if (t < 160) {
        const int k = t >> 4, o = t & 15;
        const float* pb = part + ((size_t)k * 256 + b) * O_ + o;
        float s = 0.f;
#pragma unroll
        for (int xb = 0; xb < NX; xb++)
            s += pb[(size_t)xb * BKO];
        float v = squash_v(s * (1.0f / K_));
        v1_lds[t] = v;
        v_lds[t]  = v;
    }
    __syncthreads();

    // ---- pass 2: logits from v1 ----
    sweep(ub0, ubuf, v_lds, i_l, og, wv, lane, acc);
    block_reduce(acc, red, lane, wv);
    float v12 = 0.f;
    if (t < 160) v12 = v1_lds[t] + squash_v(sum8(red, t));
    __syncthreads();          // all sum8 reads done before v_lds overwrite
    if (t < 160) v_lds[t] = v12;
    __syncthreads();

    // ---- pass 3: logits from v1+v2 (telescoped) ----
    sweep(ub0, ubuf, v_lds, i_l, og, wv, lane, acc);
    block_reduce(acc, red, lane, wv);
    if (t < 160)
        out[(size_t)b * 160 + t] = squash_v(sum8(red, t));
}

// ---------------------------------------------------------------------------
extern "C" void kernel_launch(void* const* d_in, const int* in_sizes, int n_in,
                              void* d_out, int out_size, void* d_ws, size_t ws_size,
                              hipStream_t stream)
{
    const float* x = (const float*)d_in[0];
    const float* w = (const float*)d_in[1];
    float* outp = (float*)d_out;

    float* part = (float*)d_ws;                          // NX*BKO f32 = 11.8 MB
    unsigned short* u = (unsigned short*)(part + (size_t)NX * BKO);  // 94.4 MB

    uhat_kernel<<<dim3(72, 4, 10), 256, 0, stream>>>(x, w, u, part);
    route_all<<<B_, 512, 0, stream>>>(u, part, outp);
}